// Round 15
// baseline (551.900 us; speedup 1.0000x reference)
//
#include <hip/hip_runtime.h>

#define NN     6000
#define KNN    15
#define EPB    32          // edges per node = 2*(KNN+1)
#define HID    512
#define NLAYER 3
#define OUTDIM 12000       // NN * MODES
#define MB     64          // edge rows per block (2 nodes)
#define NTH    512         // 8 waves; wave tile 64 rows x 64 cols
#define NKT    16          // k-tiles per layer (K=512 / 32)
#define NG     (NLAYER * NKT)   // 48 k-tiles total

typedef _Float16 half8  __attribute__((ext_vector_type(8)));
typedef _Float16 half4v __attribute__((ext_vector_type(4)));
typedef float    floatx4 __attribute__((ext_vector_type(4)));

// ---------- one-time: Wh fp32 [l][k][n] -> MFMA-fragment-tiled f16 ----------
// Wt = [l][kt=16][nt=32] x 1KB blocks; lane ln holds
// half8 { W[kt*32 + (ln>>4)*8 + j][nt*16 + (ln&15)] , j=0..7 }.
__global__ void prep_weights(const float* __restrict__ Wh, _Float16* __restrict__ Wt)
{
    const int blk = blockIdx.x;          // ((l*16)+kt)*32 + nt
    const int ln  = threadIdx.x;         // 0..63
    const int nt  = blk & 31;
    const int kt  = (blk >> 5) & 15;
    const int l   = blk >> 9;
    const int lc  = ln & 15, lg = ln >> 4;
    const float* src = Wh + (size_t)l * HID * HID
                          + (size_t)(kt * 32 + lg * 8) * HID + nt * 16 + lc;
    half8 v;
#pragma unroll
    for (int j = 0; j < 8; ++j) v[j] = (_Float16)src[(size_t)j * HID];
    *(half8*)(Wt + (size_t)blk * 512 + ln * 8) = v;
}

// ---------- fused MLP: B direct-to-reg (depth-2), barrier-free k-loop ----------
// LDS (dynamic): Ah [64][512] f16 XOR-swizzled = 65536 B -> 2 blocks/CU.
__global__ __launch_bounds__(NTH, 4)
void mlp_mfma_kernel(const float* __restrict__ CK,     // [NN, EPB, 3]
                     const float* __restrict__ W_in,   // [3, HID] fp32
                     const float* __restrict__ b_in,   // [HID]
                     const float* __restrict__ bh,     // [NLAYER, HID]
                     const float* __restrict__ W_out,  // [HID, 4] fp32
                     const float* __restrict__ b_out,  // [4]
                     const _Float16* __restrict__ Wt,  // tiled weights
                     float4* __restrict__ vals)        // [NN*EPB]
{
    extern __shared__ float4 smem4[];
    _Float16* Ah = (_Float16*)smem4;                   // 65536 B
    __shared__ float xs[MB * 3];

    const int t  = threadIdx.x;
    const int w  = t >> 6;          // wave 0..7 -> cols [w*64, w*64+64)
    const int ln = t & 63;
    const int lc = ln & 15;
    const int lg = ln >> 4;         // 0..3
    const int kbase = lg * 8;
    const int swzA  = (lc & 7) << 3;

    // wave's B base (half8 units): tile g at g*2048; frag nf at (w*4+nf)*64 + ln
    const half8* __restrict__ Wt8 = (const half8*)Wt + (size_t)(w * 4) * 64 + ln;

    // ---- issue B tiles 0,1 immediately (fly during input layer) ----
    half8 bA[4], bB[4];
#pragma unroll
    for (int nf = 0; nf < 4; ++nf) bA[nf] = Wt8[(size_t)0 * 2048 + nf * 64];
#pragma unroll
    for (int nf = 0; nf < 4; ++nf) bB[nf] = Wt8[(size_t)1 * 2048 + nf * 64];

    // ---- stage inputs (2 nodes = 192 floats) ----
    if (t < MB * 3) xs[t] = CK[(size_t)blockIdx.x * (MB * 3) + t];
    __syncthreads();

    // ---- input layer (fp32 VALU): one column per thread, 64 rows ----
    {
        const int j0 = t;
        const float wi0 = W_in[j0], wi1 = W_in[HID + j0], wi2 = W_in[2 * HID + j0];
        const float bi  = b_in[j0];
#pragma unroll 8
        for (int r = 0; r < MB; ++r) {
            float a = fmaf(xs[r * 3 + 2], wi2,
                      fmaf(xs[r * 3 + 1], wi1,
                      fmaf(xs[r * 3 + 0], wi0, bi)));
            Ah[r * HID + (j0 ^ ((r & 7) << 3))] = (_Float16)fmaxf(a, 0.f);
        }
    }
    __syncthreads();

    // One k-tile: A-frags from LDS, 16 MFMA from RCUR, refill RCUR <- tile G+2.
#define KSTEP(G, RCUR) do {                                                    \
        half8 a_[4];                                                           \
        const int kb_ = ((G) & 15) * 32 + kbase;                               \
        _Pragma("unroll")                                                      \
        for (int mf_ = 0; mf_ < 4; ++mf_)                                      \
            a_[mf_] = *(const half8*)&Ah[(mf_ * 16 + lc) * HID + (kb_ ^ swzA)];\
        __builtin_amdgcn_s_setprio(1);                                         \
        _Pragma("unroll")                                                      \
        for (int mf_ = 0; mf_ < 4; ++mf_)                                      \
            _Pragma("unroll")                                                  \
            for (int nf_ = 0; nf_ < 4; ++nf_)                                  \
                acc[mf_][nf_] = __builtin_amdgcn_mfma_f32_16x16x32_f16(        \
                    RCUR[nf_], a_[mf_], acc[mf_][nf_], 0, 0, 0);               \
        __builtin_amdgcn_s_setprio(0);                                         \
        if ((G) + 2 < NG) {                                                    \
            _Pragma("unroll")                                                  \
            for (int nf_ = 0; nf_ < 4; ++nf_)                                  \
                RCUR[nf_] = Wt8[(size_t)((G) + 2) * 2048 + nf_ * 64];          \
        }                                                                      \
    } while (0)

    // ---- hidden layers: barrier-free k-loop ----
    for (int layer = 0; layer < NLAYER; ++layer) {
        const float* __restrict__ bias = bh + layer * HID;

        floatx4 acc[4][4];   // operand-swapped: lane holds r=mf*16+lc, n=nf*16+lg*4+j
#pragma unroll
        for (int nf = 0; nf < 4; ++nf) {
            const floatx4 bv = *(const floatx4*)&bias[w * 64 + nf * 16 + lg * 4];
#pragma unroll
            for (int mf = 0; mf < 4; ++mf) acc[mf][nf] = bv;
        }

#pragma unroll
        for (int kt2 = 0; kt2 < NKT; kt2 += 2) {
            const int g = layer * NKT + kt2;
            KSTEP(g,     bA);
            KSTEP(g + 1, bB);
        }

        __syncthreads();   // all waves done reading Ah this layer
        // ---- writeback: relu(C^T frag) -> Ah, b64 per frag ----
#pragma unroll
        for (int mf = 0; mf < 4; ++mf) {
            const int r = mf * 16 + lc;
#pragma unroll
            for (int nf = 0; nf < 4; ++nf) {
                const int n0 = w * 64 + nf * 16 + lg * 4;
                half4v h4;
#pragma unroll
                for (int j = 0; j < 4; ++j)
                    h4[j] = (_Float16)fmaxf(acc[mf][nf][j], 0.f);
                *(half4v*)&Ah[r * HID + (n0 ^ swzA)] = h4;
            }
        }
        __syncthreads();   // new Ah visible
    }

    // ---- output layer (512 -> 4), write compact vals ----
    {
        const int s  = t & 7;       // 8 lanes per edge
        const int rr = t >> 3;      // 0..63: all 64 edges in one pass
        const int swzr = (rr & 7) << 3;
        const float4 bo = *(const float4*)b_out;
        float p0 = 0.f, p1 = 0.f, p2 = 0.f, p3 = 0.f;
        for (int i = 0; i < HID / 8; ++i) {
            const int k = s + i * 8;
            const float hv = (float)Ah[rr * HID + (k ^ swzr)];
            const floatx4 wv = *(const floatx4*)&W_out[k * 4];
            p0 = fmaf(hv, wv[0], p0);
            p1 = fmaf(hv, wv[1], p1);
            p2 = fmaf(hv, wv[2], p2);
            p3 = fmaf(hv, wv[3], p3);
        }
#pragma unroll
        for (int m = 1; m < 8; m <<= 1) {
            p0 += __shfl_xor(p0, m, 64);
            p1 += __shfl_xor(p1, m, 64);
            p2 += __shfl_xor(p2, m, 64);
            p3 += __shfl_xor(p3, m, 64);
        }
        if (s == 0)
            vals[(size_t)blockIdx.x * MB + rr] =
                make_float4(p0 + bo.x, p1 + bo.y, p2 + bo.z, p3 + bo.w);
    }
}

// ---------- writer: zeros + band accumulation, nt stores ----------
__global__ __launch_bounds__(256, 8)
void write_out(const float4* __restrict__ vals, float* __restrict__ out)
{
    const int n = blockIdx.x;
    const int t = threadIdx.x;
    __shared__ float4 v[EPB];
    __shared__ float  band[2][2 * EPB];

    if (t < EPB) v[t] = vals[(size_t)n * EPB + t];
    const int cmin  = (n - KNN < 0) ? 0 : n - KNN;
    const int cmax  = (n + KNN + 1 > NN - 1) ? NN - 1 : n + KNN + 1;
    const int width = cmax - cmin + 1;
    __syncthreads();

    if (t < width) {
        const int c = cmin + t;
        int e_lo, e_hi;
        if (c == 0)           { e_lo = 0;                  e_hi = KNN - n; }
        else if (c == NN - 1) { e_lo = (NN - 1) - n + KNN; e_hi = EPB - 1; }
        else                  { e_lo = e_hi = c - n + KNN; }
        float s0 = 0.f, s1 = 0.f, s2 = 0.f, s3 = 0.f;
        for (int e = e_lo; e <= e_hi; ++e) {
            const float4 pv = v[e];
            s0 += pv.x; s1 += pv.y; s2 += pv.z; s3 += pv.w;
        }
        band[0][2 * t] = s0; band[0][2 * t + 1] = s1;
        band[1][2 * t] = s2; band[1][2 * t + 1] = s3;
    }
    __syncthreads();

    const int j0 = 2 * cmin;
    const int w2 = 2 * width;
#pragma unroll
    for (int mi = 0; mi < 2; ++mi) {
        float* rowp = out + (size_t)(2 * n + mi) * OUTDIM;
        for (int q = t; q < OUTDIM / 4; q += 256) {
            const int j = 4 * q;
            floatx4 o;
            o[0] = ((unsigned)(j + 0 - j0) < (unsigned)w2) ? band[mi][j + 0 - j0] : 0.f;
            o[1] = ((unsigned)(j + 1 - j0) < (unsigned)w2) ? band[mi][j + 1 - j0] : 0.f;
            o[2] = ((unsigned)(j + 2 - j0) < (unsigned)w2) ? band[mi][j + 2 - j0] : 0.f;
            o[3] = ((unsigned)(j + 3 - j0) < (unsigned)w2) ? band[mi][j + 3 - j0] : 0.f;
            __builtin_nontemporal_store(o, (floatx4*)(rowp + j));
        }
    }
}

extern "C" void kernel_launch(void* const* d_in, const int* in_sizes, int n_in,
                              void* d_out, int out_size, void* d_ws, size_t ws_size,
                              hipStream_t stream) {
    const float* CK    = (const float*)d_in[0];
    const float* W_in  = (const float*)d_in[1];
    const float* b_in  = (const float*)d_in[2];
    const float* Wh    = (const float*)d_in[3];
    const float* bh    = (const float*)d_in[4];
    const float* W_out = (const float*)d_in[5];
    const float* b_out = (const float*)d_in[6];
    float* out = (float*)d_out;

    _Float16* Wt   = (_Float16*)d_ws;                          // 1.5 MB tiled
    float4*   vals = (float4*)((char*)d_ws + (size_t)3 * HID * HID * sizeof(_Float16)); // 3 MB

    (void)ws_size;
    hipFuncSetAttribute((const void*)mlp_mfma_kernel,
                        hipFuncAttributeMaxDynamicSharedMemorySize, 65536);

    prep_weights<<<NLAYER * 16 * 32, 64, 0, stream>>>(Wh, Wt);
    mlp_mfma_kernel<<<NN / 2, NTH, 65536, stream>>>(CK, W_in, b_in, bh, W_out, b_out, Wt, vals);
    write_out<<<NN, 256, 0, stream>>>(vals, out);
}

// Round 16
// 412.978 us; speedup vs baseline: 1.3364x; 1.3364x over previous
//
#include <hip/hip_runtime.h>

#define NN     6000
#define KNN    15
#define EPB    32          // edges per node = 2*(KNN+1)
#define HID    512
#define NLAYER 3
#define OUTDIM 12000       // NN * MODES
#define MB     96          // edge rows per block (3 nodes)
#define NTH    512         // 8 waves
#define NKT    16          // k-tiles per layer (K=512 / 32)
#define NG     (NLAYER * NKT)   // 48 k-tiles total

typedef _Float16 half8  __attribute__((ext_vector_type(8)));
typedef _Float16 half4v __attribute__((ext_vector_type(4)));
typedef float    floatx4 __attribute__((ext_vector_type(4)));

// ---------- one-time: Wh fp32 [l][k][n] -> MFMA-fragment-tiled f16 ----------
// Wt = [l][kt=16][nt=32] x 1KB blocks; lane ln holds
// half8 { W[kt*32 + (ln>>4)*8 + j][nt*16 + (ln&15)] , j=0..7 }.
__global__ void prep_weights(const float* __restrict__ Wh, _Float16* __restrict__ Wt)
{
    const int blk = blockIdx.x;          // ((l*16)+kt)*32 + nt
    const int ln  = threadIdx.x;         // 0..63
    const int nt  = blk & 31;
    const int kt  = (blk >> 5) & 15;
    const int l   = blk >> 9;
    const int lc  = ln & 15, lg = ln >> 4;
    const float* src = Wh + (size_t)l * HID * HID
                          + (size_t)(kt * 32 + lg * 8) * HID + nt * 16 + lc;
    half8 v;
#pragma unroll
    for (int j = 0; j < 8; ++j) v[j] = (_Float16)src[(size_t)j * HID];
    *(half8*)(Wt + (size_t)blk * 512 + ln * 8) = v;
}

// ---------- fused MLP: B direct-to-reg (depth-2) + A-frag reg double-buffer ----------
// LDS (dynamic): Ah [96][512] f16 XOR-swizzled = 98304 B. xs static.
__global__ __launch_bounds__(NTH, 1)
void mlp_mfma_kernel(const float* __restrict__ CK,     // [NN, EPB, 3]
                     const float* __restrict__ W_in,   // [3, HID] fp32
                     const float* __restrict__ b_in,   // [HID]
                     const float* __restrict__ bh,     // [NLAYER, HID]
                     const float* __restrict__ W_out,  // [HID, 4] fp32
                     const float* __restrict__ b_out,  // [4]
                     const _Float16* __restrict__ Wt,  // tiled weights
                     float4* __restrict__ vals)        // [NN*EPB]
{
    extern __shared__ float4 smem4[];
    _Float16* Ah = (_Float16*)smem4;                   // 98304 B
    __shared__ float xs[MB * 3];

    const int t  = threadIdx.x;
    const int w  = t >> 6;          // wave 0..7 -> cols [w*64, w*64+64)
    const int ln = t & 63;
    const int lc = ln & 15;
    const int lg = ln >> 4;         // 0..3
    const int kbase = lg * 8;
    const int swzA  = (lc & 7) << 3;

    // wave's B base (half8 units): tile g at g*2048; frag nf at (w*4+nf)*64 + ln
    const half8* __restrict__ Wt8 = (const half8*)Wt + (size_t)(w * 4) * 64 + ln;

    // ---- issue B tiles 0,1 immediately (fly during input layer) ----
    half8 bA[4], bB[4];
#pragma unroll
    for (int nf = 0; nf < 4; ++nf) bA[nf] = Wt8[(size_t)0 * 2048 + nf * 64];
#pragma unroll
    for (int nf = 0; nf < 4; ++nf) bB[nf] = Wt8[(size_t)1 * 2048 + nf * 64];

    // ---- stage inputs (3 nodes = 288 floats) ----
    if (t < MB * 3) xs[t] = CK[(size_t)blockIdx.x * (MB * 3) + t];
    __syncthreads();

    // ---- input layer (fp32 VALU): one column per thread, 96 rows ----
    {
        const int j0 = t;
        const float wi0 = W_in[j0], wi1 = W_in[HID + j0], wi2 = W_in[2 * HID + j0];
        const float bi  = b_in[j0];
#pragma unroll 8
        for (int r = 0; r < MB; ++r) {
            float a = fmaf(xs[r * 3 + 2], wi2,
                      fmaf(xs[r * 3 + 1], wi1,
                      fmaf(xs[r * 3 + 0], wi0, bi)));
            Ah[r * HID + (j0 ^ ((r & 7) << 3))] = (_Float16)fmaxf(a, 0.f);
        }
    }
    __syncthreads();

    half8 aA[6], aB[6];

    // read A-frags of k-tile KT into ABUF
#define LOADA(ABUF, KT) do {                                                   \
        const int kb_ = (KT) * 32 + kbase;                                     \
        _Pragma("unroll")                                                      \
        for (int mf_ = 0; mf_ < 6; ++mf_)                                      \
            ABUF[mf_] = *(const half8*)&Ah[(mf_ * 16 + lc) * HID + (kb_ ^ swzA)]; \
    } while (0)

    // One k-tile: prefetch A(kt+1) BEFORE the MFMA cluster (ds_read latency
    // hides under MFMA issue), consume ACUR, refill RCUR <- B tile G+2.
#define KSTEP(G, RCUR, ACUR, ANXT) do {                                        \
        if (((G) & 15) != 15) LOADA(ANXT, ((G) & 15) + 1);                     \
        __builtin_amdgcn_s_setprio(1);                                         \
        _Pragma("unroll")                                                      \
        for (int mf_ = 0; mf_ < 6; ++mf_)                                      \
            _Pragma("unroll")                                                  \
            for (int nf_ = 0; nf_ < 4; ++nf_)                                  \
                acc[mf_][nf_] = __builtin_amdgcn_mfma_f32_16x16x32_f16(        \
                    RCUR[nf_], ACUR[mf_], acc[mf_][nf_], 0, 0, 0);             \
        __builtin_amdgcn_s_setprio(0);                                         \
        if ((G) + 2 < NG) {                                                    \
            _Pragma("unroll")                                                  \
            for (int nf_ = 0; nf_ < 4; ++nf_)                                  \
                RCUR[nf_] = Wt8[(size_t)((G) + 2) * 2048 + nf_ * 64];          \
        }                                                                      \
    } while (0)

    // ---- hidden layers: barrier-free k-loop ----
    for (int layer = 0; layer < NLAYER; ++layer) {
        const float* __restrict__ bias = bh + layer * HID;

        floatx4 acc[6][4];   // operand-swapped: lane holds r=mf*16+lc, n=nf*16+lg*4+j
#pragma unroll
        for (int nf = 0; nf < 4; ++nf) {
            const floatx4 bv = *(const floatx4*)&bias[w * 64 + nf * 16 + lg * 4];
#pragma unroll
            for (int mf = 0; mf < 6; ++mf) acc[mf][nf] = bv;
        }

        LOADA(aA, 0);   // per-layer A prologue (Ah fresh after barrier)
#pragma unroll
        for (int kt2 = 0; kt2 < NKT; kt2 += 2) {
            const int g = layer * NKT + kt2;
            KSTEP(g,     bA, aA, aB);
            KSTEP(g + 1, bB, aB, aA);
        }

        __syncthreads();   // all waves done reading Ah this layer
        // ---- writeback: relu(C^T frag) -> Ah, b64 per frag ----
#pragma unroll
        for (int mf = 0; mf < 6; ++mf) {
            const int r = mf * 16 + lc;
#pragma unroll
            for (int nf = 0; nf < 4; ++nf) {
                const int n0 = w * 64 + nf * 16 + lg * 4;
                half4v h4;
#pragma unroll
                for (int j = 0; j < 4; ++j)
                    h4[j] = (_Float16)fmaxf(acc[mf][nf][j], 0.f);
                *(half4v*)&Ah[r * HID + (n0 ^ swzA)] = h4;
            }
        }
        __syncthreads();   // new Ah visible
    }

    // ---- output layer (512 -> 4), write compact vals ----
    {
        const int s = t & 7;
        const float4 bo = *(const float4*)b_out;
#pragma unroll
        for (int pass = 0; pass < 2; ++pass) {
            const int rr = pass * 64 + (t >> 3);
            if (rr < MB) {
                const int swzr = (rr & 7) << 3;
                float p0 = 0.f, p1 = 0.f, p2 = 0.f, p3 = 0.f;
                for (int i = 0; i < HID / 8; ++i) {
                    const int k = s + i * 8;
                    const float hv = (float)Ah[rr * HID + (k ^ swzr)];
                    const floatx4 wv = *(const floatx4*)&W_out[k * 4];
                    p0 = fmaf(hv, wv[0], p0);
                    p1 = fmaf(hv, wv[1], p1);
                    p2 = fmaf(hv, wv[2], p2);
                    p3 = fmaf(hv, wv[3], p3);
                }
#pragma unroll
                for (int m = 1; m < 8; m <<= 1) {
                    p0 += __shfl_xor(p0, m, 64);
                    p1 += __shfl_xor(p1, m, 64);
                    p2 += __shfl_xor(p2, m, 64);
                    p3 += __shfl_xor(p3, m, 64);
                }
                if (s == 0)
                    vals[(size_t)blockIdx.x * MB + rr] =
                        make_float4(p0 + bo.x, p1 + bo.y, p2 + bo.z, p3 + bo.w);
            }
        }
    }
}

// ---------- writer: zeros + band accumulation, nt stores ----------
__global__ __launch_bounds__(256, 8)
void write_out(const float4* __restrict__ vals, float* __restrict__ out)
{
    const int n = blockIdx.x;
    const int t = threadIdx.x;
    __shared__ float4 v[EPB];
    __shared__ float  band[2][2 * EPB];

    if (t < EPB) v[t] = vals[(size_t)n * EPB + t];
    const int cmin  = (n - KNN < 0) ? 0 : n - KNN;
    const int cmax  = (n + KNN + 1 > NN - 1) ? NN - 1 : n + KNN + 1;
    const int width = cmax - cmin + 1;
    __syncthreads();

    if (t < width) {
        const int c = cmin + t;
        int e_lo, e_hi;
        if (c == 0)           { e_lo = 0;                  e_hi = KNN - n; }
        else if (c == NN - 1) { e_lo = (NN - 1) - n + KNN; e_hi = EPB - 1; }
        else                  { e_lo = e_hi = c - n + KNN; }
        float s0 = 0.f, s1 = 0.f, s2 = 0.f, s3 = 0.f;
        for (int e = e_lo; e <= e_hi; ++e) {
            const float4 pv = v[e];
            s0 += pv.x; s1 += pv.y; s2 += pv.z; s3 += pv.w;
        }
        band[0][2 * t] = s0; band[0][2 * t + 1] = s1;
        band[1][2 * t] = s2; band[1][2 * t + 1] = s3;
    }
    __syncthreads();

    const int j0 = 2 * cmin;
    const int w2 = 2 * width;
#pragma unroll
    for (int mi = 0; mi < 2; ++mi) {
        float* rowp = out + (size_t)(2 * n + mi) * OUTDIM;
        for (int q = t; q < OUTDIM / 4; q += 256) {
            const int j = 4 * q;
            floatx4 o;
            o[0] = ((unsigned)(j + 0 - j0) < (unsigned)w2) ? band[mi][j + 0 - j0] : 0.f;
            o[1] = ((unsigned)(j + 1 - j0) < (unsigned)w2) ? band[mi][j + 1 - j0] : 0.f;
            o[2] = ((unsigned)(j + 2 - j0) < (unsigned)w2) ? band[mi][j + 2 - j0] : 0.f;
            o[3] = ((unsigned)(j + 3 - j0) < (unsigned)w2) ? band[mi][j + 3 - j0] : 0.f;
            __builtin_nontemporal_store(o, (floatx4*)(rowp + j));
        }
    }
}

extern "C" void kernel_launch(void* const* d_in, const int* in_sizes, int n_in,
                              void* d_out, int out_size, void* d_ws, size_t ws_size,
                              hipStream_t stream) {
    const float* CK    = (const float*)d_in[0];
    const float* W_in  = (const float*)d_in[1];
    const float* b_in  = (const float*)d_in[2];
    const float* Wh    = (const float*)d_in[3];
    const float* bh    = (const float*)d_in[4];
    const float* W_out = (const float*)d_in[5];
    const float* b_out = (const float*)d_in[6];
    float* out = (float*)d_out;

    _Float16* Wt   = (_Float16*)d_ws;                          // 1.5 MB tiled
    float4*   vals = (float4*)((char*)d_ws + (size_t)3 * HID * HID * sizeof(_Float16)); // 3 MB

    (void)ws_size;
    hipFuncSetAttribute((const void*)mlp_mfma_kernel,
                        hipFuncAttributeMaxDynamicSharedMemorySize, 98304);

    prep_weights<<<NLAYER * 16 * 32, 64, 0, stream>>>(Wh, Wt);
    mlp_mfma_kernel<<<NN / 3, NTH, 98304, stream>>>(CK, W_in, b_in, bh, W_out, b_out, Wt, vals);
    write_out<<<NN, 256, 0, stream>>>(vals, out);
}

// Round 17
// 383.618 us; speedup vs baseline: 1.4387x; 1.0765x over previous
//
#include <hip/hip_runtime.h>

#define NN     6000
#define KNN    15
#define EPB    32          // edges per node = 2*(KNN+1)
#define HID    512
#define NLAYER 3
#define OUTDIM 12000       // NN * MODES
#define MB     96          // edge rows per block (3 nodes)
#define NTH    512         // 8 waves
#define NKT    16          // k-tiles per layer (K=512 / 32)
#define NG     (NLAYER * NKT)   // 48 k-tiles total

typedef _Float16 half8  __attribute__((ext_vector_type(8)));
typedef _Float16 half4v __attribute__((ext_vector_type(4)));
typedef float    floatx4 __attribute__((ext_vector_type(4)));

// ---------- one-time: Wh fp32 [l][k][n] -> MFMA-fragment-tiled f16 ----------
// Wt = [l][kt=16][nt=32] x 1KB blocks; lane ln holds
// half8 { W[kt*32 + (ln>>4)*8 + j][nt*16 + (ln&15)] , j=0..7 }.
__global__ void prep_weights(const float* __restrict__ Wh, _Float16* __restrict__ Wt)
{
    const int blk = blockIdx.x;          // ((l*16)+kt)*32 + nt
    const int ln  = threadIdx.x;         // 0..63
    const int nt  = blk & 31;
    const int kt  = (blk >> 5) & 15;
    const int l   = blk >> 9;
    const int lc  = ln & 15, lg = ln >> 4;
    const float* src = Wh + (size_t)l * HID * HID
                          + (size_t)(kt * 32 + lg * 8) * HID + nt * 16 + lc;
    half8 v;
#pragma unroll
    for (int j = 0; j < 8; ++j) v[j] = (_Float16)src[(size_t)j * HID];
    *(half8*)(Wt + (size_t)blk * 512 + ln * 8) = v;
}

// ---------- fused MLP + in-kernel zeroing + direct band write ----------
// Block m owns output rows [6m, 6m+6) exclusively: zeros them (band window
// skipped) overlapped with the k-loops, writes the band window at the end.
// LDS (dynamic): Ah [96][512] f16 XOR-swizzled = 98304 B.
__global__ __launch_bounds__(NTH, 1)
void mlp_mfma_kernel(const float* __restrict__ CK,     // [NN, EPB, 3]
                     const float* __restrict__ W_in,   // [3, HID] fp32
                     const float* __restrict__ b_in,   // [HID]
                     const float* __restrict__ bh,     // [NLAYER, HID]
                     const float* __restrict__ W_out,  // [HID, 4] fp32
                     const float* __restrict__ b_out,  // [4]
                     const _Float16* __restrict__ Wt,  // tiled weights
                     float* __restrict__ out)          // [OUTDIM*OUTDIM]
{
    extern __shared__ float4 smem4[];
    _Float16* Ah = (_Float16*)smem4;                   // 98304 B
    __shared__ float  xs[MB * 3];
    __shared__ float4 edgeval[MB];                     // per-edge MLP outputs
    __shared__ float  bandv[3][2][80];                 // per-node band values

    const int t  = threadIdx.x;
    const int w  = t >> 6;          // wave 0..7 -> cols [w*64, w*64+64)
    const int ln = t & 63;
    const int lc = ln & 15;
    const int lg = ln >> 4;         // 0..3
    const int kbase = lg * 8;
    const int swzA  = (lc & 7) << 3;
    const int m  = blockIdx.x;      // 0..1999

    // zero one owned output row (band window skipped), nt full-line stores
    const floatx4 z4 = (floatx4){0.f, 0.f, 0.f, 0.f};
#define ZROW(Q) do {                                                           \
        const int n_   = 3 * m + ((Q) >> 1);                                   \
        const int cmin_ = (n_ - KNN < 0) ? 0 : n_ - KNN;                       \
        const int cmax_ = (n_ + KNN + 1 > NN - 1) ? NN - 1 : n_ + KNN + 1;     \
        const int end_  = 2 * cmin_ + 2 * (cmax_ - cmin_ + 1);                 \
        const int wlo_  = (2 * cmin_) & ~3;                                    \
        const int whi_  = (end_ + 3) & ~3;                                     \
        float* rowp_ = out + (size_t)(6 * m + (Q)) * OUTDIM;                   \
        for (int i_ = t; i_ < OUTDIM / 4; i_ += NTH) {                         \
            const int j_ = 4 * i_;                                             \
            if (j_ < wlo_ || j_ >= whi_)                                       \
                __builtin_nontemporal_store(z4, (floatx4*)(rowp_ + j_));       \
        }                                                                      \
    } while (0)

    // wave's B base (half8 units): tile g at g*2048; frag nf at (w*4+nf)*64 + ln
    const half8* __restrict__ Wt8 = (const half8*)Wt + (size_t)(w * 4) * 64 + ln;

    // ---- issue B tiles 0,1 immediately (fly during input layer) ----
    half8 bA[4], bB[4];
#pragma unroll
    for (int nf = 0; nf < 4; ++nf) bA[nf] = Wt8[(size_t)0 * 2048 + nf * 64];
#pragma unroll
    for (int nf = 0; nf < 4; ++nf) bB[nf] = Wt8[(size_t)1 * 2048 + nf * 64];

    // ---- stage inputs (3 nodes = 288 floats) ----
    if (t < MB * 3) xs[t] = CK[(size_t)m * (MB * 3) + t];
    __syncthreads();

    // ---- input layer (fp32 VALU): one column per thread, 96 rows ----
    {
        const int j0 = t;
        const float wi0 = W_in[j0], wi1 = W_in[HID + j0], wi2 = W_in[2 * HID + j0];
        const float bi  = b_in[j0];
#pragma unroll 8
        for (int r = 0; r < MB; ++r) {
            float a = fmaf(xs[r * 3 + 2], wi2,
                      fmaf(xs[r * 3 + 1], wi1,
                      fmaf(xs[r * 3 + 0], wi0, bi)));
            Ah[r * HID + (j0 ^ ((r & 7) << 3))] = (_Float16)fmaxf(a, 0.f);
        }
    }
    __syncthreads();

    // One k-tile: A-frags from LDS, 24 MFMA from RCUR, refill RCUR <- tile G+2.
#define KSTEP(G, RCUR) do {                                                    \
        half8 a_[6];                                                           \
        const int kb_ = ((G) & 15) * 32 + kbase;                               \
        _Pragma("unroll")                                                      \
        for (int mf_ = 0; mf_ < 6; ++mf_)                                      \
            a_[mf_] = *(const half8*)&Ah[(mf_ * 16 + lc) * HID + (kb_ ^ swzA)];\
        __builtin_amdgcn_s_setprio(1);                                         \
        _Pragma("unroll")                                                      \
        for (int mf_ = 0; mf_ < 6; ++mf_)                                      \
            _Pragma("unroll")                                                  \
            for (int nf_ = 0; nf_ < 4; ++nf_)                                  \
                acc[mf_][nf_] = __builtin_amdgcn_mfma_f32_16x16x32_f16(        \
                    RCUR[nf_], a_[mf_], acc[mf_][nf_], 0, 0, 0);               \
        __builtin_amdgcn_s_setprio(0);                                         \
        if ((G) + 2 < NG) {                                                    \
            _Pragma("unroll")                                                  \
            for (int nf_ = 0; nf_ < 4; ++nf_)                                  \
                RCUR[nf_] = Wt8[(size_t)((G) + 2) * 2048 + nf_ * 64];          \
        }                                                                      \
    } while (0)

    // ---- hidden layers: barrier-free k-loop, zero stores overlapped ----
    for (int layer = 0; layer < NLAYER; ++layer) {
        const float* __restrict__ bias = bh + layer * HID;

        floatx4 acc[6][4];   // operand-swapped: lane holds r=mf*16+lc, n=nf*16+lg*4+j
#pragma unroll
        for (int nf = 0; nf < 4; ++nf) {
            const floatx4 bv = *(const floatx4*)&bias[w * 64 + nf * 16 + lg * 4];
#pragma unroll
            for (int mf = 0; mf < 6; ++mf) acc[mf][nf] = bv;
        }

        // issue 2 rows of zeros; they drain under this layer's ~13us k-loop
        ZROW(layer * 2);
        ZROW(layer * 2 + 1);

#pragma unroll
        for (int kt2 = 0; kt2 < NKT; kt2 += 2) {
            const int g = layer * NKT + kt2;
            KSTEP(g,     bA);
            KSTEP(g + 1, bB);
        }

        __syncthreads();   // all waves done reading Ah this layer
        // ---- writeback: relu(C^T frag) -> Ah, b64 per frag ----
#pragma unroll
        for (int mf = 0; mf < 6; ++mf) {
            const int r = mf * 16 + lc;
#pragma unroll
            for (int nf = 0; nf < 4; ++nf) {
                const int n0 = w * 64 + nf * 16 + lg * 4;
                half4v h4;
#pragma unroll
                for (int j = 0; j < 4; ++j)
                    h4[j] = (_Float16)fmaxf(acc[mf][nf][j], 0.f);
                *(half4v*)&Ah[r * HID + (n0 ^ swzA)] = h4;
            }
        }
        __syncthreads();   // new Ah visible
    }

    // ---- output layer (512 -> 4) -> edgeval in LDS ----
    {
        const int s = t & 7;
        const float4 bo = *(const float4*)b_out;
#pragma unroll
        for (int pass = 0; pass < 2; ++pass) {
            const int rr = pass * 64 + (t >> 3);
            if (rr < MB) {
                const int swzr = (rr & 7) << 3;
                float p0 = 0.f, p1 = 0.f, p2 = 0.f, p3 = 0.f;
                for (int i = 0; i < HID / 8; ++i) {
                    const int k = s + i * 8;
                    const float hv = (float)Ah[rr * HID + (k ^ swzr)];
                    const floatx4 wv = *(const floatx4*)&W_out[k * 4];
                    p0 = fmaf(hv, wv[0], p0);
                    p1 = fmaf(hv, wv[1], p1);
                    p2 = fmaf(hv, wv[2], p2);
                    p3 = fmaf(hv, wv[3], p3);
                }
#pragma unroll
                for (int mm = 1; mm < 8; mm <<= 1) {
                    p0 += __shfl_xor(p0, mm, 64);
                    p1 += __shfl_xor(p1, mm, 64);
                    p2 += __shfl_xor(p2, mm, 64);
                    p3 += __shfl_xor(p3, mm, 64);
                }
                if (s == 0)
                    edgeval[rr] = make_float4(p0 + bo.x, p1 + bo.y,
                                              p2 + bo.z, p3 + bo.w);
            }
        }
    }
    __syncthreads();

    // ---- band composition (write_out logic, in-block, deterministic) ----
    if (t < 96) {
        const int nd = t >> 5, ci = t & 31;
        const int n  = 3 * m + nd;
        const int cmin  = (n - KNN < 0) ? 0 : n - KNN;
        const int cmax  = (n + KNN + 1 > NN - 1) ? NN - 1 : n + KNN + 1;
        const int width = cmax - cmin + 1;
        if (ci < width) {
            const int c = cmin + ci;
            int e_lo, e_hi;
            if (c == 0)           { e_lo = 0;                  e_hi = KNN - n; }
            else if (c == NN - 1) { e_lo = (NN - 1) - n + KNN; e_hi = EPB - 1; }
            else                  { e_lo = e_hi = c - n + KNN; }
            float s0 = 0.f, s1 = 0.f, s2 = 0.f, s3 = 0.f;
            for (int e = e_lo; e <= e_hi; ++e) {
                const float4 pv = edgeval[nd * EPB + e];
                s0 += pv.x; s1 += pv.y; s2 += pv.z; s3 += pv.w;
            }
            bandv[nd][0][2 * ci] = s0; bandv[nd][0][2 * ci + 1] = s1;
            bandv[nd][1][2 * ci] = s2; bandv[nd][1][2 * ci + 1] = s3;
        }
    }
    __syncthreads();

    // ---- write the 6 band windows (16B-aligned; zeros outside band) ----
    if (t < 6 * 80) {
        const int q  = t / 80;          // row 0..5
        const int jl = t % 80;
        const int nd = q >> 1, mi = q & 1;
        const int n  = 3 * m + nd;
        const int cmin  = (n - KNN < 0) ? 0 : n - KNN;
        const int cmax  = (n + KNN + 1 > NN - 1) ? NN - 1 : n + KNN + 1;
        const int end   = 2 * cmin + 2 * (cmax - cmin + 1);
        const int wlo   = (2 * cmin) & ~3;
        const int whi   = (end + 3) & ~3;
        const int j     = wlo + jl;
        if (j < whi) {
            const bool inside = (j >= 2 * cmin) && (j < end);
            const float v = inside ? bandv[nd][mi][j - 2 * cmin] : 0.f;
            out[(size_t)(6 * m + q) * OUTDIM + j] = v;
        }
    }
}

extern "C" void kernel_launch(void* const* d_in, const int* in_sizes, int n_in,
                              void* d_out, int out_size, void* d_ws, size_t ws_size,
                              hipStream_t stream) {
    const float* CK    = (const float*)d_in[0];
    const float* W_in  = (const float*)d_in[1];
    const float* b_in  = (const float*)d_in[2];
    const float* Wh    = (const float*)d_in[3];
    const float* bh    = (const float*)d_in[4];
    const float* W_out = (const float*)d_in[5];
    const float* b_out = (const float*)d_in[6];
    float* out = (float*)d_out;

    _Float16* Wt = (_Float16*)d_ws;    // 1.5 MB tiled weights

    (void)ws_size;
    hipFuncSetAttribute((const void*)mlp_mfma_kernel,
                        hipFuncAttributeMaxDynamicSharedMemorySize, 98304);

    prep_weights<<<NLAYER * 16 * 32, 64, 0, stream>>>(Wh, Wt);
    mlp_mfma_kernel<<<NN / 3, NTH, 98304, stream>>>(CK, W_in, b_in, bh,
                                                    W_out, b_out, Wt, out);
}